// Round 1
// baseline (816.417 us; speedup 1.0000x reference)
//
#include <hip/hip_runtime.h>
#include <hip/hip_bf16.h>
#include <math.h>

#define H 2048
#define S 4096
#define B 16
#define POOL 4096
#define EPS 1e-6f
#define INV_SQRT_H 0.022097086912079608f   // 1/sqrt(2048)

// Workspace layout (floats):
//   q      : [0      , 2048)
//   qk     : [2048   , 4096)
//   num    : [4096   , 36864)   -- B*H
//   den    : [36864  , 36880)   -- B
//   pv     : [36880  , 69648)   -- B*H (pooled after Wv)
//   normed : [69648  , 102416)  -- B*H
#define OFF_Q     0
#define OFF_QK    2048
#define OFF_NUM   4096
#define OFF_DEN   36864
#define OFF_PV    36880
#define OFF_NORM  69648

__device__ __forceinline__ float wave_reduce(float v) {
#pragma unroll
  for (int off = 32; off > 0; off >>= 1) v += __shfl_xor(v, off, 64);
  return v;
}

__global__ __launch_bounds__(256) void k_zero(float* __restrict__ p, int n) {
  int i = blockIdx.x * 256 + threadIdx.x;
  if (i < n) p[i] = 0.f;
}

// q[d] = sum_h lq[h] * Wq[d*H + h]   (one wave per d)
__global__ __launch_bounds__(256) void k_q(const float* __restrict__ Wq,
                                           const float* __restrict__ lq,
                                           float* __restrict__ q) {
  const int d = blockIdx.x * 4 + (threadIdx.x >> 6);
  const int lane = threadIdx.x & 63;
  const float4* row = (const float4*)(Wq + (size_t)d * H);
  const float4* l4  = (const float4*)lq;
  float acc = 0.f;
#pragma unroll
  for (int k = 0; k < H / 4 / 64; ++k) {
    float4 w = row[lane + k * 64];
    float4 x = l4[lane + k * 64];
    acc += w.x * x.x + w.y * x.y + w.z * x.z + w.w * x.w;
  }
  acc = wave_reduce(acc);
  if (lane == 0) q[d] = acc;
}

// qk[h] += sum_{d in chunk} q[d] * Wk[d*H + h]
// grid (H/256, 32 d-chunks of 64)
__global__ __launch_bounds__(256) void k_qk(const float* __restrict__ Wk,
                                            const float* __restrict__ q,
                                            float* __restrict__ qk) {
  const int h  = blockIdx.x * 256 + threadIdx.x;
  const int d0 = blockIdx.y * 64;
  float local = 0.f;
#pragma unroll 8
  for (int dd = 0; dd < 64; ++dd) {
    local += q[d0 + dd] * Wk[(size_t)(d0 + dd) * H + h];
  }
  atomicAdd(&qk[h], local);
}

// Single pass over X: scores + unnormalized-softmax weighted column sums.
// grid (S/128, B). Each thread owns 8 columns (c0 = tid*8).
__global__ __launch_bounds__(256) void k_main(const float* __restrict__ X,
                                              const int* __restrict__ mask,
                                              const float* __restrict__ qk,
                                              float* __restrict__ num,
                                              float* __restrict__ den) {
  const int b  = blockIdx.y;
  const int s0 = blockIdx.x * 128;
  const int t  = threadIdx.x;
  const int c0 = t * 8;
  const int lane = t & 63;
  const int wv   = t >> 6;

  __shared__ float red[4][4];

  const float4 qa = *(const float4*)(qk + c0);
  const float4 qb = *(const float4*)(qk + c0 + 4);

  float acc[8];
#pragma unroll
  for (int j = 0; j < 8; ++j) acc[j] = 0.f;
  float denl = 0.f;

  const float* Xb = X + (size_t)b * S * H;
  const int*   mb = mask + b * S;

  for (int sb = 0; sb < 128; sb += 4) {
    float4 xa[4], xbv[4];
#pragma unroll
    for (int r = 0; r < 4; ++r) {
      const float* xp = Xb + (size_t)(s0 + sb + r) * H + c0;
      xa[r]  = *(const float4*)xp;
      xbv[r] = *(const float4*)(xp + 4);
      float p = xa[r].x * qa.x + xa[r].y * qa.y + xa[r].z * qa.z + xa[r].w * qa.w
              + xbv[r].x * qb.x + xbv[r].y * qb.y + xbv[r].z * qb.z + xbv[r].w * qb.w;
      p = wave_reduce(p);
      if (lane == 0) red[r][wv] = p;
    }
    __syncthreads();
#pragma unroll
    for (int r = 0; r < 4; ++r) {
      const int s = s0 + sb + r;
      float score = (red[r][0] + red[r][1] + red[r][2] + red[r][3]) * INV_SQRT_H;
      float w = mb[s] ? __expf(score) : 0.f;
      denl += w;
      acc[0] += w * xa[r].x;  acc[1] += w * xa[r].y;
      acc[2] += w * xa[r].z;  acc[3] += w * xa[r].w;
      acc[4] += w * xbv[r].x; acc[5] += w * xbv[r].y;
      acc[6] += w * xbv[r].z; acc[7] += w * xbv[r].w;
    }
    __syncthreads();
  }

#pragma unroll
  for (int j = 0; j < 8; ++j) atomicAdd(&num[b * H + c0 + j], acc[j]);
  if (t == 0) atomicAdd(&den[b], denl);
}

// pv[b,d] = (1/den[b]) * sum_h Wv[d*H+h] * num[b*H+h]   (one wave per d, 16 b-accumulators)
__global__ __launch_bounds__(256) void k_pv(const float* __restrict__ Wv,
                                            const float* __restrict__ num,
                                            const float* __restrict__ den,
                                            float* __restrict__ pv) {
  const int d = blockIdx.x * 4 + (threadIdx.x >> 6);
  const int lane = threadIdx.x & 63;
  const float4* wrow = (const float4*)(Wv + (size_t)d * H);
  const float4* n4   = (const float4*)num;
  float acc[B];
#pragma unroll
  for (int bb = 0; bb < B; ++bb) acc[bb] = 0.f;
  for (int k = lane; k < H / 4; k += 64) {
    float4 w = wrow[k];
#pragma unroll
    for (int bb = 0; bb < B; ++bb) {
      float4 v = n4[bb * (H / 4) + k];
      acc[bb] += w.x * v.x + w.y * v.y + w.z * v.z + w.w * v.w;
    }
  }
#pragma unroll
  for (int bb = 0; bb < B; ++bb) acc[bb] = wave_reduce(acc[bb]);
  if (lane == 0) {
#pragma unroll
    for (int bb = 0; bb < B; ++bb) pv[bb * H + d] = acc[bb] / den[bb];
  }
}

// RMS norm over H per batch. One block per b.
__global__ __launch_bounds__(256) void k_rms(const float* __restrict__ pv,
                                             const float* __restrict__ nw,
                                             float* __restrict__ normed) {
  const int b = blockIdx.x;
  const int t = threadIdx.x;
  __shared__ float sred[4];
  float ss = 0.f;
  for (int h = t; h < H; h += 256) {
    float v = pv[b * H + h];
    ss += v * v;
  }
  ss = wave_reduce(ss);
  if ((t & 63) == 0) sred[t >> 6] = ss;
  __syncthreads();
  float tot = sred[0] + sred[1] + sred[2] + sred[3];
  float sc = rsqrtf(tot / (float)H + EPS);
  for (int h = t; h < H; h += 256) normed[b * H + h] = pv[b * H + h] * sc * nw[h];
}

// out[b,p] = sum_d normed[b,d] * Wo[p*H+d]   (one wave per p, 16 b-accumulators)
__global__ __launch_bounds__(256) void k_out(const float* __restrict__ Wo,
                                             const float* __restrict__ normed,
                                             float* __restrict__ out) {
  const int p = blockIdx.x * 4 + (threadIdx.x >> 6);
  const int lane = threadIdx.x & 63;
  const float4* wrow = (const float4*)(Wo + (size_t)p * H);
  const float4* n4   = (const float4*)normed;
  float acc[B];
#pragma unroll
  for (int bb = 0; bb < B; ++bb) acc[bb] = 0.f;
  for (int k = lane; k < H / 4; k += 64) {
    float4 w = wrow[k];
#pragma unroll
    for (int bb = 0; bb < B; ++bb) {
      float4 v = n4[bb * (H / 4) + k];
      acc[bb] += w.x * v.x + w.y * v.y + w.z * v.z + w.w * v.w;
    }
  }
#pragma unroll
  for (int bb = 0; bb < B; ++bb) acc[bb] = wave_reduce(acc[bb]);
  if (lane == 0) {
#pragma unroll
    for (int bb = 0; bb < B; ++bb) out[bb * POOL + p] = acc[bb];
  }
}

extern "C" void kernel_launch(void* const* d_in, const int* in_sizes, int n_in,
                              void* d_out, int out_size, void* d_ws, size_t ws_size,
                              hipStream_t stream) {
  (void)in_sizes; (void)n_in; (void)out_size; (void)ws_size;
  const float* X    = (const float*)d_in[0];
  const int*   mask = (const int*)d_in[1];
  const float* lq   = (const float*)d_in[2];
  const float* Wq   = (const float*)d_in[3];
  const float* Wk   = (const float*)d_in[4];
  const float* Wv   = (const float*)d_in[5];
  const float* Wo   = (const float*)d_in[6];
  const float* nw   = (const float*)d_in[7];
  float* out = (float*)d_out;
  float* ws  = (float*)d_ws;

  float* q      = ws + OFF_Q;
  float* qk     = ws + OFF_QK;
  float* num    = ws + OFF_NUM;
  float* den    = ws + OFF_DEN;
  float* pv     = ws + OFF_PV;
  float* normed = ws + OFF_NORM;

  // zero qk + num + den (contiguous: [OFF_QK, OFF_PV) = 34832 floats)
  {
    int n = OFF_PV - OFF_QK;
    k_zero<<<(n + 255) / 256, 256, 0, stream>>>(ws + OFF_QK, n);
  }
  k_q<<<H / 4, 256, 0, stream>>>(Wq, lq, q);
  k_qk<<<dim3(H / 256, 32), 256, 0, stream>>>(Wk, q, qk);
  k_main<<<dim3(S / 128, B), 256, 0, stream>>>(X, mask, qk, num, den);
  k_pv<<<H / 4, 256, 0, stream>>>(Wv, num, den, pv);
  k_rms<<<B, 256, 0, stream>>>(pv, nw, normed);
  k_out<<<POOL / 4, 256, 0, stream>>>(Wo, normed, out);
}

// Round 2
// 781.609 us; speedup vs baseline: 1.0445x; 1.0445x over previous
//
#include <hip/hip_runtime.h>
#include <hip/hip_bf16.h>
#include <math.h>

#define H 2048
#define S 4096
#define B 16
#define POOL 4096
#define EPS 1e-6f
#define INV_SQRT_H 0.022097086912079608f   // 1/sqrt(2048)

// Workspace layout (floats):
#define OFF_Q     0          // [0, 2048)       q = Wq @ lq
#define OFF_QK    2048       // [2048, 4096)    qk = Wk^T @ q
#define OFF_NUM   4096       // [4096, 36864)   B*H unnormalized weighted sums
#define OFF_DEN   36864      // [36864, 36880)  B softmax denominators
#define OFF_SSQ   36880      // [36880, 36896)  B sum-of-squares for RMS
#define OFF_PV    36896      // [36896, 69664)  B*H pooled * norm_w
#define ZERO_BEG  OFF_QK
#define ZERO_END  (OFF_SSQ + 16)   // 36896

__device__ __forceinline__ float wave_reduce(float v) {
#pragma unroll
  for (int off = 32; off > 0; off >>= 1) v += __shfl_xor(v, off, 64);
  return v;
}

// q[d] = sum_h lq[h] * Wq[d*H + h]   (one wave per d); also zeroes scratch.
__global__ __launch_bounds__(256) void k_q(const float* __restrict__ Wq,
                                           const float* __restrict__ lq,
                                           float* __restrict__ ws) {
  // zero [ZERO_BEG, ZERO_END): 34848 floats over first 137 blocks
  {
    int i = ZERO_BEG + blockIdx.x * 256 + threadIdx.x;
    if (blockIdx.x < 137 && i < ZERO_END) ws[i] = 0.f;
  }
  const int d = blockIdx.x * 4 + (threadIdx.x >> 6);
  const int lane = threadIdx.x & 63;
  const float4* row = (const float4*)(Wq + (size_t)d * H);
  const float4* l4  = (const float4*)lq;
  float acc = 0.f;
#pragma unroll
  for (int k = 0; k < H / 4 / 64; ++k) {
    float4 w = row[lane + k * 64];
    float4 x = l4[lane + k * 64];
    acc += w.x * x.x + w.y * x.y + w.z * x.z + w.w * x.w;
  }
  acc = wave_reduce(acc);
  if (lane == 0) ws[OFF_Q + d] = acc;
}

// qk[h] += sum_{d in chunk} q[d] * Wk[d*H + h];  grid (H/256, 32)
__global__ __launch_bounds__(256) void k_qk(const float* __restrict__ Wk,
                                            const float* __restrict__ ws_q,
                                            float* __restrict__ qk) {
  const int h  = blockIdx.x * 256 + threadIdx.x;
  const int d0 = blockIdx.y * 64;
  float local = 0.f;
#pragma unroll 8
  for (int dd = 0; dd < 64; ++dd) {
    local += ws_q[d0 + dd] * Wk[(size_t)(d0 + dd) * H + h];
  }
  atomicAdd(&qk[h], local);
}

// Wave-autonomous single pass over X. grid (S/128, B), 256 threads.
// Wave w owns rows [s0+32w, s0+32w+32); lane l owns cols 4*(l+64k), k=0..7.
// Rows with mask==0 are skipped entirely (w=0 exactly) -> ~50% less X traffic.
__global__ __launch_bounds__(256) void k_main(const float* __restrict__ X,
                                              const int* __restrict__ mask,
                                              const float* __restrict__ qk,
                                              float* __restrict__ num,
                                              float* __restrict__ den) {
  const int b  = blockIdx.y;
  const int s0 = blockIdx.x * 128;
  const int t  = threadIdx.x;
  const int lane = t & 63;
  const int wv   = t >> 6;

  __shared__ float lnum[H];
  __shared__ float lden;
#pragma unroll
  for (int j = 0; j < 8; ++j) lnum[t * 8 + j] = 0.f;
  if (t == 0) lden = 0.f;

  float4 qv[8];
#pragma unroll
  for (int k = 0; k < 8; ++k) qv[k] = *(const float4*)(qk + 4 * (lane + 64 * k));

  float4 acc[8];
#pragma unroll
  for (int k = 0; k < 8; ++k) acc[k] = make_float4(0.f, 0.f, 0.f, 0.f);
  float denl = 0.f;

  const int srow0 = s0 + wv * 32;
  const float* Xw = X + (size_t)b * S * H + (size_t)srow0 * H;
  const int*   mb = mask + b * S + srow0;

  __syncthreads();  // lnum zeroing visible before end-of-loop atomics

  for (int r = 0; r < 32; ++r) {
    if (mb[r] == 0) continue;          // wave-uniform skip: no load, no flops
    const float* xp = Xw + (size_t)r * H;
    float4 x[8];
#pragma unroll
    for (int k = 0; k < 8; ++k) x[k] = *(const float4*)(xp + 4 * (lane + 64 * k));
    float p = 0.f;
#pragma unroll
    for (int k = 0; k < 8; ++k)
      p += x[k].x * qv[k].x + x[k].y * qv[k].y + x[k].z * qv[k].z + x[k].w * qv[k].w;
    p = wave_reduce(p);
    float w = __expf(p * INV_SQRT_H);
    denl += w;
#pragma unroll
    for (int k = 0; k < 8; ++k) {
      acc[k].x += w * x[k].x; acc[k].y += w * x[k].y;
      acc[k].z += w * x[k].z; acc[k].w += w * x[k].w;
    }
  }

  // block combine in LDS (4-way contention max), then one global atomic/elem
#pragma unroll
  for (int k = 0; k < 8; ++k) {
    const int c = 4 * (lane + 64 * k);
    atomicAdd(&lnum[c + 0], acc[k].x);
    atomicAdd(&lnum[c + 1], acc[k].y);
    atomicAdd(&lnum[c + 2], acc[k].z);
    atomicAdd(&lnum[c + 3], acc[k].w);
  }
  if (lane == 0) atomicAdd(&lden, denl);
  __syncthreads();
#pragma unroll
  for (int j = 0; j < 8; ++j) atomicAdd(&num[b * H + t * 8 + j], lnum[t * 8 + j]);
  if (t == 0) atomicAdd(&den[b], lden);
}

// pv[b,d] = nw[d] * (num[b]·Wv_row_d)/den[b]; also accumulate ssq[b] partials.
__global__ __launch_bounds__(256) void k_pv(const float* __restrict__ Wv,
                                            const float* __restrict__ num,
                                            const float* __restrict__ den,
                                            const float* __restrict__ nw,
                                            float* __restrict__ pv,
                                            float* __restrict__ ssq) {
  const int d = blockIdx.x * 4 + (threadIdx.x >> 6);
  const int lane = threadIdx.x & 63;
  const int wv   = threadIdx.x >> 6;
  const float4* wrow = (const float4*)(Wv + (size_t)d * H);
  const float4* n4   = (const float4*)num;
  float acc[B];
#pragma unroll
  for (int bb = 0; bb < B; ++bb) acc[bb] = 0.f;
  for (int k = lane; k < H / 4; k += 64) {
    float4 w = wrow[k];
#pragma unroll
    for (int bb = 0; bb < B; ++bb) {
      float4 v = n4[bb * (H / 4) + k];
      acc[bb] += w.x * v.x + w.y * v.y + w.z * v.z + w.w * v.w;
    }
  }
#pragma unroll
  for (int bb = 0; bb < B; ++bb) acc[bb] = wave_reduce(acc[bb]);

  __shared__ float sblk[4][B];
  if (lane == 0) {
    const float nwd = nw[d];
#pragma unroll
    for (int bb = 0; bb < B; ++bb) {
      float p = acc[bb] / den[bb];
      pv[bb * H + d] = p * nwd;
      sblk[wv][bb] = p * p;
    }
  }
  __syncthreads();
  if (threadIdx.x < B) {
    atomicAdd(&ssq[threadIdx.x],
              sblk[0][threadIdx.x] + sblk[1][threadIdx.x] +
              sblk[2][threadIdx.x] + sblk[3][threadIdx.x]);
  }
}

// out[b,p] = rsqrt(ssq[b]/H+eps) * sum_d pv[b,d] * Wo[p*H+d]
__global__ __launch_bounds__(256) void k_out(const float* __restrict__ Wo,
                                             const float* __restrict__ pv,
                                             const float* __restrict__ ssq,
                                             float* __restrict__ out) {
  const int p = blockIdx.x * 4 + (threadIdx.x >> 6);
  const int lane = threadIdx.x & 63;
  const float4* wrow = (const float4*)(Wo + (size_t)p * H);
  const float4* n4   = (const float4*)pv;
  float acc[B];
#pragma unroll
  for (int bb = 0; bb < B; ++bb) acc[bb] = 0.f;
  for (int k = lane; k < H / 4; k += 64) {
    float4 w = wrow[k];
#pragma unroll
    for (int bb = 0; bb < B; ++bb) {
      float4 v = n4[bb * (H / 4) + k];
      acc[bb] += w.x * v.x + w.y * v.y + w.z * v.z + w.w * v.w;
    }
  }
#pragma unroll
  for (int bb = 0; bb < B; ++bb) acc[bb] = wave_reduce(acc[bb]);
  if (lane == 0) {
#pragma unroll
    for (int bb = 0; bb < B; ++bb) {
      float sc = rsqrtf(ssq[bb] * (1.0f / (float)H) + EPS);
      out[bb * POOL + p] = acc[bb] * sc;
    }
  }
}

extern "C" void kernel_launch(void* const* d_in, const int* in_sizes, int n_in,
                              void* d_out, int out_size, void* d_ws, size_t ws_size,
                              hipStream_t stream) {
  (void)in_sizes; (void)n_in; (void)out_size; (void)ws_size;
  const float* X    = (const float*)d_in[0];
  const int*   mask = (const int*)d_in[1];
  const float* lq   = (const float*)d_in[2];
  const float* Wq   = (const float*)d_in[3];
  const float* Wk   = (const float*)d_in[4];
  const float* Wv   = (const float*)d_in[5];
  const float* Wo   = (const float*)d_in[6];
  const float* nw   = (const float*)d_in[7];
  float* out = (float*)d_out;
  float* ws  = (float*)d_ws;

  k_q   <<<H / 4, 256, 0, stream>>>(Wq, lq, ws);
  k_qk  <<<dim3(H / 256, 32), 256, 0, stream>>>(Wk, ws + OFF_Q, ws + OFF_QK);
  k_main<<<dim3(S / 128, B), 256, 0, stream>>>(X, mask, ws + OFF_QK,
                                               ws + OFF_NUM, ws + OFF_DEN);
  k_pv  <<<H / 4, 256, 0, stream>>>(Wv, ws + OFF_NUM, ws + OFF_DEN, nw,
                                    ws + OFF_PV, ws + OFF_SSQ);
  k_out <<<POOL / 4, 256, 0, stream>>>(Wo, ws + OFF_PV, ws + OFF_SSQ, out);
}